// Round 14
// baseline (1714.467 us; speedup 1.0000x reference)
//
#include <hip/hip_runtime.h>
#include <stdint.h>

#define NDIM 16384
#define M_TOP 22
#define NCHUNK 64

typedef float  fvec4  __attribute__((ext_vector_type(4)));
typedef float  f32x4  __attribute__((ext_vector_type(4)));
typedef __bf16 bf16x8 __attribute__((ext_vector_type(8)));
typedef unsigned short u16x8 __attribute__((ext_vector_type(8)));
typedef unsigned short u16x4 __attribute__((ext_vector_type(4)));

static_assert(sizeof(bf16x8) == 16, "bf16x8 must be 16B");
static_assert(sizeof(u16x8) == 16, "u16x8 must be 16B");

// ---------- helpers ----------

__device__ __forceinline__ unsigned short bf16r(float x) {
  unsigned u = __builtin_bit_cast(unsigned, x);
  return (unsigned short)((u + 0x7FFFu + ((u >> 16) & 1u)) >> 16);
}

// monotone f32 <-> u32 order-preserving map (exact, bijective)
__device__ __forceinline__ unsigned fmap(float x) {
  unsigned u = __builtin_bit_cast(unsigned, x);
  return u ^ (unsigned)(((int)u >> 31) | (int)0x80000000);
}
__device__ __forceinline__ float funmap(unsigned m) {
  unsigned u = (m & 0x80000000u) ? (m ^ 0x80000000u) : ~m;
  return __builtin_bit_cast(float, u);
}

// global -> LDS direct copy, 16B per lane (linear dest per wave)
__device__ __forceinline__ void gload_lds16(const void* g, void* l) {
  typedef __attribute__((address_space(1))) const unsigned int gas_u32;
  typedef __attribute__((address_space(3))) unsigned int las_u32;
  __builtin_amdgcn_global_load_lds((gas_u32*)(uintptr_t)g,
                                   (las_u32*)(unsigned)(uintptr_t)l, 16, 0, 0);
}

#define MEMFENCE asm volatile("" ::: "memory")
#define BARRIER_LG do { asm volatile("s_waitcnt lgkmcnt(0)" ::: "memory"); \
                        __builtin_amdgcn_s_barrier(); MEMFENCE; } while (0)

// =====================================================================
// K1: fused linears: q->qf(fp32)+Bpack(hi bf16, swizzled), k->kf+Apack,
//     Am = x@Wm1a^T, Bm = x@Wm1b^T + bm1, XU = x@Wu1a^T + bu1
// =====================================================================
__global__ __launch_bounds__(256, 1) void k1_linears(
    const float* __restrict__ x,
    const float* __restrict__ Wq, const float* __restrict__ bq,
    const float* __restrict__ Wk, const float* __restrict__ bk,
    const float* __restrict__ Wm1, const float* __restrict__ bm1,
    const float* __restrict__ Wu1, const float* __restrict__ bu1,
    unsigned short* __restrict__ Apack, unsigned short* __restrict__ Bpack,
    float* __restrict__ qf, float* __restrict__ kf,
    float* __restrict__ Am, float* __restrict__ Bm, float* __restrict__ XU)
{
  extern __shared__ char lds[];
  float* xs = (float*)lds;              // 32768 B, [64][128] quad-swizzled
  float* wT = (float*)(lds + 32768);    // 65536 B, [c][co]

  const int t = threadIdx.x;
  const int rbase = blockIdx.x * 64;
  const int tr = t >> 4, tc = t & 15;

#pragma unroll
  for (int i = 0; i < 8; ++i) {
    int flat = (i * 256 + t) * 4;
    int row = flat >> 7, c = flat & 127;
    fvec4 v = *(const fvec4*)(x + (size_t)(rbase + row) * 128 + c);
    int q = (c >> 2) ^ ((row >> 2) & 7);
    *(fvec4*)(xs + row * 128 + q * 4) = v;
  }

  for (int s = 0; s < 5; ++s) {
    const float* W; int wstride, coff; const float* bias;
    if (s == 0)      { W = Wq;  wstride = 128; coff = 0;   bias = bq; }
    else if (s == 1) { W = Wk;  wstride = 128; coff = 0;   bias = bk; }
    else if (s == 2) { W = Wm1; wstride = 256; coff = 0;   bias = nullptr; }
    else if (s == 3) { W = Wm1; wstride = 256; coff = 128; bias = bm1; }
    else             { W = Wu1; wstride = 256; coff = 0;   bias = bu1; }

    __syncthreads();
    {
      int co = t >> 1, c0 = (t & 1) * 64;
      const float* wr = W + (size_t)co * wstride + coff + c0;
#pragma unroll
      for (int i = 0; i < 16; ++i) {
        fvec4 v = *(const fvec4*)(wr + 4 * i);
        wT[(c0 + 4 * i + 0) * 128 + co] = v[0];
        wT[(c0 + 4 * i + 1) * 128 + co] = v[1];
        wT[(c0 + 4 * i + 2) * 128 + co] = v[2];
        wT[(c0 + 4 * i + 3) * 128 + co] = v[3];
      }
    }
    __syncthreads();

    float acc[4][8];
#pragma unroll
    for (int rr = 0; rr < 4; ++rr)
#pragma unroll
      for (int i = 0; i < 8; ++i) acc[rr][i] = 0.f;

    for (int cq = 0; cq < 32; ++cq) {
      fvec4 xv[4];
#pragma unroll
      for (int rr = 0; rr < 4; ++rr)
        xv[rr] = *(const fvec4*)(xs + (tr * 4 + rr) * 128 + ((cq ^ (tr & 7)) << 2));
#pragma unroll
      for (int j = 0; j < 4; ++j) {
        int c = cq * 4 + j;
        fvec4 wa = *(const fvec4*)(wT + c * 128 + tc * 4);
        fvec4 wb = *(const fvec4*)(wT + c * 128 + 64 + tc * 4);
#pragma unroll
        for (int rr = 0; rr < 4; ++rr) {
          float xj = xv[rr][j];
#pragma unroll
          for (int i = 0; i < 4; ++i) {
            acc[rr][i]     += xj * wa[i];
            acc[rr][4 + i] += xj * wb[i];
          }
        }
      }
    }

    float ba[4] = {0, 0, 0, 0}, bb[4] = {0, 0, 0, 0};
    if (bias) {
      fvec4 t0 = *(const fvec4*)(bias + tc * 4);
      fvec4 t1 = *(const fvec4*)(bias + 64 + tc * 4);
#pragma unroll
      for (int i = 0; i < 4; ++i) { ba[i] = t0[i]; bb[i] = t1[i]; }
    }

#pragma unroll
    for (int rr = 0; rr < 4; ++rr) {
      int row = rbase + tr * 4 + rr;
      float v0[4], v1[4];
#pragma unroll
      for (int i = 0; i < 4; ++i) {
        v0[i] = acc[rr][i] + ba[i];
        v1[i] = acc[rr][4 + i] + bb[i];
      }
      fvec4 w0 = {v0[0], v0[1], v0[2], v0[3]};
      fvec4 w1 = {v1[0], v1[1], v1[2], v1[3]};
      if (s >= 2) {
        float* dst = (s == 2 ? Am : (s == 3 ? Bm : XU)) + (size_t)row * 128;
        *(fvec4*)(dst + tc * 4) = w0;
        *(fvec4*)(dst + 64 + tc * 4) = w1;
      } else {
        float* fdst = (s == 0 ? qf : kf) + (size_t)row * 128;
        *(fvec4*)(fdst + tc * 4) = w0;
        *(fvec4*)(fdst + 64 + tc * 4) = w1;
        unsigned short h0[4], h1[4];
#pragma unroll
        for (int i = 0; i < 4; ++i) { h0[i] = bf16r(v0[i]); h1[i] = bf16r(v1[i]); }
        u16x4 H0 = {h0[0], h0[1], h0[2], h0[3]};
        u16x4 H1 = {h1[0], h1[1], h1[2], h1[3]};
        if (s == 1) {   // k -> Apack, plain hi layout (128 shorts/row)
          unsigned short* dst = Apack + (size_t)row * 128;
          *(u16x4*)(dst + tc * 4) = H0;
          *(u16x4*)(dst + 64 + tc * 4) = H1;
        } else {        // q -> Bpack, group-swizzled hi (128 shorts/row)
          int jm = row & 7;
          int p0 = (((tc >> 1) ^ jm) << 3) | ((tc & 1) << 2);
          int p1 = (((8 + (tc >> 1)) ^ jm) << 3) | ((tc & 1) << 2);
          unsigned short* dst = Bpack + (size_t)row * 128;
          *(u16x4*)(dst + p0) = H0;
          *(u16x4*)(dst + p1) = H1;
        }
      }
    }
  }
}

// =====================================================================
// K2: hi.hi bf16 GEMM (K=128), per-LANE top-22 of EXACT (f32, j) pairs.
// grid 512 = 256 row-tiles(64 rows) x 2 j-halves; 512 thr = 8 waves.
// == r11 structure + kg-pre-reduced threshold publish, with the +4 VGPR
// bill paid by M_TOP 24->22 (margin-2 = 7.5 sigma vs hi-noise; exactness
// certificates unchanged). __launch_bounds__(512,8) hard-caps VGPR at 64
// (the measured residency cliff: 64 -> 2 blocks/CU, 68 -> 1 block/CU).
// =====================================================================
__global__ __launch_bounds__(512, 8) void k2_simtopk(
    const unsigned short* __restrict__ Apack, const unsigned short* __restrict__ Bpack,
    float* __restrict__ plv, int* __restrict__ pli)
{
  extern __shared__ char lds[];                   // 65536 staging + 256 thr
  unsigned* thr = (unsigned*)(lds + 65536);       // [64], mapped domain
  float* exv = (float*)lds;                       // epilogue overlay on buf0
  int*   exj = (int*)(lds + 6144);                // epilogue overlay on buf0

  const int t = threadIdx.x;
  const int lane = t & 63, wid = t >> 6;
  const int wjj = wid & 1, wii = wid >> 1;        // wjj 0..1, wii 0..3
  const int tile = blockIdx.x >> 1, jh = blockIdx.x & 1;
  const int rbase = tile * 64;
  const int jstart = jh * 8192;
  const int l15 = lane & 15, kg = lane >> 4;
  const int row = wii * 16 + l15;                 // this lane's row (0..63)

  if (t < 64) thr[t] = fmap(-3.0e38f);

  // ---- k-hi fragment: ONE row per lane (B operand col = l15) ----
  u16x8 kh[4];
  {
    const unsigned short* arow = Apack + (size_t)(rbase + row) * 128;
#pragma unroll
    for (int ks = 0; ks < 4; ++ks)
      kh[ks] = *(const u16x8*)(arow + ks * 32 + kg * 8);
  }

  // ---- per-lane top-22 (exact value, global j), descending ----
  float lv[M_TOP]; int li[M_TOP];
#pragma unroll
  for (int s = 0; s < M_TOP; ++s) { lv[s] = -3.0e38f; li[s] = 0; }

  auto insert = [&](float v, int j) {
    float cv = v; int ci = j;
#pragma unroll
    for (int s = 0; s < M_TOP; ++s) {
      bool m = cv > lv[s];
      float tv = lv[s]; int ti = li[s];
      lv[s] = m ? cv : tv; li[s] = m ? ci : ti;
      cv = m ? tv : cv;   ci = m ? ti : ci;
    }
  };

  // ---- per-lane LDS byte offsets for q-frags (XOR bank swizzle) ----
  int loff[4];
#pragma unroll
  for (int ksl = 0; ksl < 4; ++ksl)
    loff[ksl] = l15 * 256 + ((ksl * 64 + kg * 16) ^ ((l15 & 7) << 4));

  auto stage = [&](int ch) {
    if (ch >= NCHUNK) ch -= NCHUNK;   // tail wrap: dummy re-stage keeps vmcnt math
    int jb = jstart + ch * 128;
    char* base = lds + (ch & 1) * 32768;
#pragma unroll
    for (int i = 0; i < 4; ++i) {
      int L = (i * 512 + t) * 16;
      int r2 = L >> 8, bir = L & 255;
      gload_lds16((const char*)Bpack + (size_t)(jb + r2) * 256 + bir, base + L);
    }
  };

  // prologue: two chunks in flight (4 loads each)
  stage(0);
  stage(1);

  for (int chunk = 0; chunk < NCHUNK; ++chunk) {
    // buf landed; prior ds writes (thr init / thr atomics) drained for visibility
    asm volatile("s_waitcnt vmcnt(4) lgkmcnt(0)" ::: "memory");
    __builtin_amdgcn_s_barrier();                 // (a) buf + thr coherent
    MEMFENCE;

    unsigned mthr = thr[row];                     // broadcast read; used post-MFMA

    f32x4 acc[4];
#pragma unroll
    for (int jj = 0; jj < 4; ++jj) acc[jj] = (f32x4){0.f, 0.f, 0.f, 0.f};

    const char* buf = lds + (chunk & 1) * 32768 + wjj * 16384;
#pragma unroll
    for (int ksl = 0; ksl < 4; ++ksl) {
      bf16x8 q[4];
#pragma unroll
      for (int jj = 0; jj < 4; ++jj)
        q[jj] = __builtin_bit_cast(bf16x8, *(const u16x8*)(buf + jj * 4096 + loff[ksl]));
#pragma unroll
      for (int jj = 0; jj < 4; ++jj)
        acc[jj] = __builtin_amdgcn_mfma_f32_16x16x32_bf16(
            q[jj], __builtin_bit_cast(bf16x8, kh[ksl]), acc[jj], 0, 0, 0);
    }

    BARRIER_LG;                                   // (b) buf reads done
    stage(chunk + 2);                             // overwrite consumed buffer

    const float thrf = funmap(mthr);

    // ---- per-jj candidate masks + drain (in-loop mask: short liveness) ----
    const int jb2 = jstart + chunk * 128 + wjj * 64 + kg * 4;
#pragma unroll
    for (int jj = 0; jj < 4; ++jj) {
      f32x4 f = acc[jj];
      unsigned mj = 0;
#pragma unroll
      for (int r = 0; r < 4; ++r)
        mj |= (f[r] > thrf) ? (1u << r) : 0u;
      while (mj) {
        int r = __builtin_ctz(mj); mj &= mj - 1;
        float v01 = (r & 1) ? f[1] : f[0];
        float v23 = (r & 1) ? f[3] : f[2];
        float v = (r & 2) ? v23 : v01;
        if (v > lv[M_TOP - 1]) insert(v, jb2 + jj * 16 + r);
      }
    }

    // ---- publish row threshold: pre-reduce over 4 kg lanes, 1 atomic ----
    {
      float th = lv[M_TOP - 1];
      th = fmaxf(th, __shfl_xor(th, 16, 64));
      th = fmaxf(th, __shfl_xor(th, 32, 64));
      if (kg == 0 && th > thrf) atomicMax(&thr[row], fmap(th));
    }
  }
  asm volatile("s_waitcnt vmcnt(0)" ::: "memory");    // my tail dummy stages done

  // ---- merge the 4 kg-lane lists of each row (xor 16, then 32) ----
  for (int d = 16; d <= 32; d <<= 1) {
    float sv[M_TOP]; int sj[M_TOP];
#pragma unroll
    for (int s = 0; s < M_TOP; ++s) { sv[s] = lv[s]; sj[s] = li[s]; }
#pragma unroll
    for (int s = 0; s < M_TOP; ++s) {
      float pv = __shfl_xor(sv[s], d, 64);
      int pj = __shfl_xor(sj[s], d, 64);
      if (pv > lv[M_TOP - 1]) insert(pv, pj);
    }
  }

  __builtin_amdgcn_s_barrier();   // ALL waves' dummy-stage writes to buf0 done
  MEMFENCE;

  // ---- cross-wjj merge via LDS overlay; wjj==0 kg==0 lanes finish ----
  if (wjj == 1 && kg == 0) {
#pragma unroll
    for (int s = 0; s < M_TOP; ++s) {
      exv[row * M_TOP + s] = lv[s];
      exj[row * M_TOP + s] = li[s];
    }
  }
  BARRIER_LG;   // partner lists visible block-wide
  if (wjj == 0 && kg == 0) {
    for (int s = 0; s < M_TOP; ++s) {
      float pv = exv[row * M_TOP + s];
      if (!(pv > lv[M_TOP - 1])) break;   // descending -> done
      insert(pv, exj[row * M_TOP + s]);
    }
    float* pv = plv + ((size_t)jh * NDIM + rbase + row) * M_TOP;
    int* pi = pli + ((size_t)jh * NDIM + rbase + row) * M_TOP;
#pragma unroll
    for (int s = 0; s < M_TOP; ++s) { pv[s] = lv[s]; pi[s] = li[s]; }
  }
}

// =====================================================================
// K2c: merge 2x22 hi-lists -> top-22, rescore exact fp32 (qf,kf),
//      select true top-20 + softmax. 64 rows per block.
// =====================================================================
__global__ __launch_bounds__(256) void k2c_rescore(
    const float* __restrict__ plv, const int* __restrict__ pli,
    const float* __restrict__ qf, const float* __restrict__ kf,
    float* __restrict__ score, int* __restrict__ idx)
{
  __shared__ int   midx[64][M_TOP];
  __shared__ float simv[64][M_TOP];
  const int t = threadIdx.x;
  const int rbase = blockIdx.x * 64;

  if (t < 64) {
    int r = rbase + t;
    const float* v0 = plv + ((size_t)0 * NDIM + r) * M_TOP;
    const float* v1 = plv + ((size_t)1 * NDIM + r) * M_TOP;
    const int* i0 = pli + ((size_t)0 * NDIM + r) * M_TOP;
    const int* i1 = pli + ((size_t)1 * NDIM + r) * M_TOP;
    int p0 = 0, p1 = 0;
    float a = v0[0], b = v1[0];
#pragma unroll
    for (int s = 0; s < M_TOP; ++s) {
      bool ta = (a >= b);
      midx[t][s] = ta ? i0[p0] : i1[p1];
      if (ta) { ++p0; a = (p0 < M_TOP) ? v0[p0] : -3.0e38f; }
      else    { ++p1; b = (p1 < M_TOP) ? v1[p1] : -3.0e38f; }
    }
  }
  __syncthreads();
  {
    int r = t >> 2, g = t & 3;
    const float* krow = kf + (size_t)(rbase + r) * 128;
#pragma unroll
    for (int s = 0; s < 6; ++s) {
      int c = g * 6 + s;
      if (c >= M_TOP) break;
      int j = midx[r][c];
      const float* qrow = qf + (size_t)j * 128;
      fvec4 a4 = {0.f, 0.f, 0.f, 0.f};
#pragma unroll
      for (int i = 0; i < 32; ++i) {
        fvec4 kv = *(const fvec4*)(krow + i * 4);
        fvec4 qv = *(const fvec4*)(qrow + i * 4);
        a4 += kv * qv;
      }
      simv[r][c] = a4[0] + a4[1] + a4[2] + a4[3];
    }
  }
  __syncthreads();
  if (t < 64) {
    float lv[20]; int li[20];
#pragma unroll
    for (int s = 0; s < 20; ++s) { lv[s] = -3.0e38f; li[s] = 0; }
    for (int c = 0; c < M_TOP; ++c) {
      float v = simv[t][c]; int j = midx[t][c];
      if (v > lv[19]) {
        float cv = v; int ci = j;
#pragma unroll
        for (int s = 0; s < 20; ++s) {
          bool m = cv > lv[s];
          float tv = lv[s]; int ti = li[s];
          lv[s] = m ? cv : tv; li[s] = m ? ci : ti;
          cv = m ? tv : cv;   ci = m ? ti : ci;
        }
      }
    }
    float vmax = lv[0], sum = 0.f;
    float e[20];
#pragma unroll
    for (int s = 0; s < 20; ++s) { e[s] = expf(lv[s] - vmax); sum += e[s]; }
    float inv = 1.0f / sum;
    float* sc = score + (size_t)(rbase + t) * 20;
    int* ix = idx + (size_t)(rbase + t) * 20;
#pragma unroll
    for (int s = 0; s < 20; ++s) { sc[s] = e[s] * inv; ix[s] = li[s]; }
  }
}

// =====================================================================
// K3a: R[i] = sum_k score_k * relu(Am_i + Bm_{j_k})
// =====================================================================
__global__ __launch_bounds__(256) void k3a_gather(
    const float* __restrict__ Am, const float* __restrict__ Bm,
    const float* __restrict__ score, const int* __restrict__ idx,
    float* __restrict__ R)
{
  int t = threadIdx.x;
  int node = blockIdx.x * 32 + (t >> 3);
  int c0 = (t & 7) * 16;
  const float* am = Am + (size_t)node * 128 + c0;
  fvec4 a[4], r[4];
#pragma unroll
  for (int i = 0; i < 4; ++i) {
    a[i] = *(const fvec4*)(am + 4 * i);
    r[i] = (fvec4){0.f, 0.f, 0.f, 0.f};
  }
  const float* sc = score + (size_t)node * 20;
  const int* ix = idx + (size_t)node * 20;
  for (int k = 0; k < 20; ++k) {
    int j = ix[k]; float s = sc[k];
    const float* bm = Bm + (size_t)j * 128 + c0;
#pragma unroll
    for (int i = 0; i < 4; ++i) {
      fvec4 b = *(const fvec4*)(bm + 4 * i);
#pragma unroll
      for (int q = 0; q < 4; ++q)
        r[i][q] += s * fmaxf(a[i][q] + b[q], 0.f);
    }
  }
  float* outp = R + (size_t)node * 128 + c0;
#pragma unroll
  for (int i = 0; i < 4; ++i) *(fvec4*)(outp + 4 * i) = r[i];
}

// =====================================================================
// K3b: out = x + relu(XU + (R@Wm2^T + bm2)@Wu1b^T)@Wu2^T + bu2
// =====================================================================
__global__ __launch_bounds__(256, 1) void k3b_update(
    const float* __restrict__ R, const float* __restrict__ XU, const float* __restrict__ x,
    const float* __restrict__ Wm2, const float* __restrict__ bm2,
    const float* __restrict__ Wu1, const float* __restrict__ Wu2, const float* __restrict__ bu2,
    float* __restrict__ outg)
{
  extern __shared__ char lds[];
  float* in0 = (float*)lds;             // 32768
  float* in1 = (float*)(lds + 32768);   // 32768
  float* wT  = (float*)(lds + 65536);   // 65536

  const int t = threadIdx.x;
  const int rbase = blockIdx.x * 64;
  const int tr = t >> 4, tc = t & 15;

#pragma unroll
  for (int i = 0; i < 8; ++i) {
    int flat = (i * 256 + t) * 4;
    int row = flat >> 7, c = flat & 127;
    fvec4 v = *(const fvec4*)(R + (size_t)(rbase + row) * 128 + c);
    *(fvec4*)(in0 + row * 128 + (((c >> 2) ^ ((row >> 2) & 7)) << 2)) = v;
  }

  for (int s = 0; s < 3; ++s) {
    const float* W; int wstride, coff;
    if (s == 0)      { W = Wm2; wstride = 128; coff = 0; }
    else if (s == 1) { W = Wu1; wstride = 256; coff = 128; }
    else             { W = Wu2; wstride = 128; coff = 0; }

    __syncthreads();
    {
      int co = t >> 1, c0 = (t & 1) * 64;
      const float* wr = W + (size_t)co * wstride + coff + c0;
#pragma unroll
      for (int i = 0; i < 16; ++i) {
        fvec4 v = *(const fvec4*)(wr + 4 * i);
        wT[(c0 + 4 * i + 0) * 128 + co] = v[0];
        wT[(c0 + 4 * i + 1) * 128 + co] = v[1];
        wT[(c0 + 4 * i + 2) * 128 + co] = v[2];
        wT[(c0 + 4 * i + 3) * 128 + co] = v[3];
      }
    }
    __syncthreads();

    const float* in = (s == 1) ? in1 : in0;
    float acc[4][8];
#pragma unroll
    for (int rr = 0; rr < 4; ++rr)
#pragma unroll
      for (int i = 0; i < 8; ++i) acc[rr][i] = 0.f;

    for (int cq = 0; cq < 32; ++cq) {
      fvec4 xv[4];
#pragma unroll
      for (int rr = 0; rr < 4; ++rr)
        xv[rr] = *(const fvec4*)(in + (tr * 4 + rr) * 128 + ((cq ^ (tr & 7)) << 2));
#pragma unroll
      for (int j = 0; j < 4; ++j) {
        int c = cq * 4 + j;
        fvec4 wa = *(const fvec4*)(wT + c * 128 + tc * 4);
        fvec4 wb = *(const fvec4*)(wT + c * 128 + 64 + tc * 4);
#pragma unroll
        for (int rr = 0; rr < 4; ++rr) {
          float xj = xv[rr][j];
#pragma unroll
          for (int i = 0; i < 4; ++i) {
            acc[rr][i]     += xj * wa[i];
            acc[rr][4 + i] += xj * wb[i];
          }
        }
      }
    }

#pragma unroll
    for (int rr = 0; rr < 4; ++rr) {
      int row = rbase + tr * 4 + rr;
      int lrow = tr * 4 + rr;
      int q0 = tc ^ (tr & 7);
      int q1 = (16 + tc) ^ (tr & 7);
      if (s == 0) {
        fvec4 b0 = *(const fvec4*)(bm2 + tc * 4);
        fvec4 b1 = *(const fvec4*)(bm2 + 64 + tc * 4);
        fvec4 w0, w1;
#pragma unroll
        for (int i = 0; i < 4; ++i) { w0[i] = acc[rr][i] + b0[i]; w1[i] = acc[rr][4 + i] + b1[i]; }
        *(fvec4*)(in1 + lrow * 128 + q0 * 4) = w0;
        *(fvec4*)(in1 + lrow * 128 + q1 * 4) = w1;
      } else if (s == 1) {
        fvec4 x0 = *(const fvec4*)(XU + (size_t)row * 128 + tc * 4);
        fvec4 x1 = *(const fvec4*)(XU + (size_t)row * 128 + 64 + tc * 4);
        fvec4 w0, w1;
#pragma unroll
        for (int i = 0; i < 4; ++i) {
          w0[i] = fmaxf(acc[rr][i] + x0[i], 0.f);
          w1[i] = fmaxf(acc[rr][4 + i] + x1[i], 0.f);
        }
        *(fvec4*)(in0 + lrow * 128 + q0 * 4) = w0;
        *(fvec4*)(in0 + lrow * 128 + q1 * 4) = w1;
      } else {
        fvec4 b0 = *(const fvec4*)(bu2 + tc * 4);
        fvec4 b1 = *(const fvec4*)(bu2 + 64 + tc * 4);
        fvec4 x0 = *(const fvec4*)(x + (size_t)row * 128 + tc * 4);
        fvec4 x1 = *(const fvec4*)(x + (size_t)row * 128 + 64 + tc * 4);
        fvec4 w0, w1;
#pragma unroll
        for (int i = 0; i < 4; ++i) {
          w0[i] = x0[i] + acc[rr][i] + b0[i];
          w1[i] = x1[i] + acc[rr][4 + i] + b1[i];
        }
        *(fvec4*)(outg + (size_t)row * 128 + tc * 4) = w0;
        *(fvec4*)(outg + (size_t)row * 128 + 64 + tc * 4) = w1;
      }
    }
    __syncthreads();
  }
}

// =====================================================================
// launch
// =====================================================================
extern "C" void kernel_launch(void* const* d_in, const int* in_sizes, int n_in,
                              void* d_out, int out_size, void* d_ws, size_t ws_size,
                              hipStream_t stream) {
  const float* x   = (const float*)d_in[0];
  const float* Wq  = (const float*)d_in[1];
  const float* bq  = (const float*)d_in[2];
  const float* Wk  = (const float*)d_in[3];
  const float* bk  = (const float*)d_in[4];
  const float* Wm1 = (const float*)d_in[5];
  const float* bm1 = (const float*)d_in[6];
  const float* Wm2 = (const float*)d_in[7];
  const float* bm2 = (const float*)d_in[8];
  const float* Wu1 = (const float*)d_in[9];
  const float* bu1 = (const float*)d_in[10];
  const float* Wu2 = (const float*)d_in[11];
  const float* bu2 = (const float*)d_in[12];
  float* outp = (float*)d_out;

  const size_t NN = NDIM;
  char* w = (char*)d_ws;
  unsigned short* Apack = (unsigned short*)w; w += NN * 128 * 2;
  unsigned short* Bpack = (unsigned short*)w; w += NN * 128 * 2;
  float* qf = (float*)w; w += NN * 128 * 4;
  float* kf = (float*)w; w += NN * 128 * 4;
  float* Am = (float*)w; w += NN * 128 * 4;
  float* Bm = (float*)w; w += NN * 128 * 4;
  float* XU = (float*)w; w += NN * 128 * 4;
  char* w_plv = w;
  float* plv = (float*)w; w += 4 * NN * M_TOP * 4;   // (2 used; 4 kept for R overlay room)
  int* pli = (int*)w; w += 4 * NN * M_TOP * 4;
  float* score = (float*)w; w += NN * 20 * 4;
  int* idxb = (int*)w; w += NN * 20 * 4;
  float* R = (float*)w_plv;   // overlays plv/pli (dead after k2c)

  hipFuncSetAttribute((const void*)k1_linears, hipFuncAttributeMaxDynamicSharedMemorySize, 98304);
  hipFuncSetAttribute((const void*)k2_simtopk, hipFuncAttributeMaxDynamicSharedMemorySize, 65792);
  hipFuncSetAttribute((const void*)k3b_update, hipFuncAttributeMaxDynamicSharedMemorySize, 131072);

  k1_linears<<<256, 256, 98304, stream>>>(x, Wq, bq, Wk, bk, Wm1, bm1, Wu1, bu1,
                                          Apack, Bpack, qf, kf, Am, Bm, XU);
  k2_simtopk<<<512, 512, 65792, stream>>>(Apack, Bpack, plv, pli);
  k2c_rescore<<<256, 256, 0, stream>>>(plv, pli, qf, kf, score, idxb);
  k3a_gather<<<512, 256, 0, stream>>>(Am, Bm, score, idxb, R);
  k3b_update<<<256, 256, 131072, stream>>>(R, XU, x, Wm2, bm2, Wu1, Wu2, bu2, outp);
}

// Round 15
// 687.720 us; speedup vs baseline: 2.4930x; 2.4930x over previous
//
#include <hip/hip_runtime.h>
#include <stdint.h>

#define NDIM 16384
#define M_TOP 22
#define NCHUNK 64

typedef float  fvec4  __attribute__((ext_vector_type(4)));
typedef float  f32x4  __attribute__((ext_vector_type(4)));
typedef __bf16 bf16x8 __attribute__((ext_vector_type(8)));
typedef unsigned short u16x8 __attribute__((ext_vector_type(8)));
typedef unsigned short u16x4 __attribute__((ext_vector_type(4)));

static_assert(sizeof(bf16x8) == 16, "bf16x8 must be 16B");
static_assert(sizeof(u16x8) == 16, "u16x8 must be 16B");

// ---------- helpers ----------

__device__ __forceinline__ unsigned short bf16r(float x) {
  unsigned u = __builtin_bit_cast(unsigned, x);
  return (unsigned short)((u + 0x7FFFu + ((u >> 16) & 1u)) >> 16);
}

// monotone f32 <-> u32 order-preserving map (exact, bijective)
__device__ __forceinline__ unsigned fmap(float x) {
  unsigned u = __builtin_bit_cast(unsigned, x);
  return u ^ (unsigned)(((int)u >> 31) | (int)0x80000000);
}
__device__ __forceinline__ float funmap(unsigned m) {
  unsigned u = (m & 0x80000000u) ? (m ^ 0x80000000u) : ~m;
  return __builtin_bit_cast(float, u);
}

// global -> LDS direct copy, 16B per lane (linear dest per wave)
__device__ __forceinline__ void gload_lds16(const void* g, void* l) {
  typedef __attribute__((address_space(1))) const unsigned int gas_u32;
  typedef __attribute__((address_space(3))) unsigned int las_u32;
  __builtin_amdgcn_global_load_lds((gas_u32*)(uintptr_t)g,
                                   (las_u32*)(unsigned)(uintptr_t)l, 16, 0, 0);
}

#define MEMFENCE asm volatile("" ::: "memory")
#define BARRIER_LG do { asm volatile("s_waitcnt lgkmcnt(0)" ::: "memory"); \
                        __builtin_amdgcn_s_barrier(); MEMFENCE; } while (0)

// =====================================================================
// K1: fused linears: q->qf(fp32)+Bpack(hi bf16, swizzled), k->kf+Apack,
//     Am = x@Wm1a^T, Bm = x@Wm1b^T + bm1, XU = x@Wu1a^T + bu1
// =====================================================================
__global__ __launch_bounds__(256, 1) void k1_linears(
    const float* __restrict__ x,
    const float* __restrict__ Wq, const float* __restrict__ bq,
    const float* __restrict__ Wk, const float* __restrict__ bk,
    const float* __restrict__ Wm1, const float* __restrict__ bm1,
    const float* __restrict__ Wu1, const float* __restrict__ bu1,
    unsigned short* __restrict__ Apack, unsigned short* __restrict__ Bpack,
    float* __restrict__ qf, float* __restrict__ kf,
    float* __restrict__ Am, float* __restrict__ Bm, float* __restrict__ XU)
{
  extern __shared__ char lds[];
  float* xs = (float*)lds;              // 32768 B, [64][128] quad-swizzled
  float* wT = (float*)(lds + 32768);    // 65536 B, [c][co]

  const int t = threadIdx.x;
  const int rbase = blockIdx.x * 64;
  const int tr = t >> 4, tc = t & 15;

#pragma unroll
  for (int i = 0; i < 8; ++i) {
    int flat = (i * 256 + t) * 4;
    int row = flat >> 7, c = flat & 127;
    fvec4 v = *(const fvec4*)(x + (size_t)(rbase + row) * 128 + c);
    int q = (c >> 2) ^ ((row >> 2) & 7);
    *(fvec4*)(xs + row * 128 + q * 4) = v;
  }

  for (int s = 0; s < 5; ++s) {
    const float* W; int wstride, coff; const float* bias;
    if (s == 0)      { W = Wq;  wstride = 128; coff = 0;   bias = bq; }
    else if (s == 1) { W = Wk;  wstride = 128; coff = 0;   bias = bk; }
    else if (s == 2) { W = Wm1; wstride = 256; coff = 0;   bias = nullptr; }
    else if (s == 3) { W = Wm1; wstride = 256; coff = 128; bias = bm1; }
    else             { W = Wu1; wstride = 256; coff = 0;   bias = bu1; }

    __syncthreads();
    {
      int co = t >> 1, c0 = (t & 1) * 64;
      const float* wr = W + (size_t)co * wstride + coff + c0;
#pragma unroll
      for (int i = 0; i < 16; ++i) {
        fvec4 v = *(const fvec4*)(wr + 4 * i);
        wT[(c0 + 4 * i + 0) * 128 + co] = v[0];
        wT[(c0 + 4 * i + 1) * 128 + co] = v[1];
        wT[(c0 + 4 * i + 2) * 128 + co] = v[2];
        wT[(c0 + 4 * i + 3) * 128 + co] = v[3];
      }
    }
    __syncthreads();

    float acc[4][8];
#pragma unroll
    for (int rr = 0; rr < 4; ++rr)
#pragma unroll
      for (int i = 0; i < 8; ++i) acc[rr][i] = 0.f;

    for (int cq = 0; cq < 32; ++cq) {
      fvec4 xv[4];
#pragma unroll
      for (int rr = 0; rr < 4; ++rr)
        xv[rr] = *(const fvec4*)(xs + (tr * 4 + rr) * 128 + ((cq ^ (tr & 7)) << 2));
#pragma unroll
      for (int j = 0; j < 4; ++j) {
        int c = cq * 4 + j;
        fvec4 wa = *(const fvec4*)(wT + c * 128 + tc * 4);
        fvec4 wb = *(const fvec4*)(wT + c * 128 + 64 + tc * 4);
#pragma unroll
        for (int rr = 0; rr < 4; ++rr) {
          float xj = xv[rr][j];
#pragma unroll
          for (int i = 0; i < 4; ++i) {
            acc[rr][i]     += xj * wa[i];
            acc[rr][4 + i] += xj * wb[i];
          }
        }
      }
    }

    float ba[4] = {0, 0, 0, 0}, bb[4] = {0, 0, 0, 0};
    if (bias) {
      fvec4 t0 = *(const fvec4*)(bias + tc * 4);
      fvec4 t1 = *(const fvec4*)(bias + 64 + tc * 4);
#pragma unroll
      for (int i = 0; i < 4; ++i) { ba[i] = t0[i]; bb[i] = t1[i]; }
    }

#pragma unroll
    for (int rr = 0; rr < 4; ++rr) {
      int row = rbase + tr * 4 + rr;
      float v0[4], v1[4];
#pragma unroll
      for (int i = 0; i < 4; ++i) {
        v0[i] = acc[rr][i] + ba[i];
        v1[i] = acc[rr][4 + i] + bb[i];
      }
      fvec4 w0 = {v0[0], v0[1], v0[2], v0[3]};
      fvec4 w1 = {v1[0], v1[1], v1[2], v1[3]};
      if (s >= 2) {
        float* dst = (s == 2 ? Am : (s == 3 ? Bm : XU)) + (size_t)row * 128;
        *(fvec4*)(dst + tc * 4) = w0;
        *(fvec4*)(dst + 64 + tc * 4) = w1;
      } else {
        float* fdst = (s == 0 ? qf : kf) + (size_t)row * 128;
        *(fvec4*)(fdst + tc * 4) = w0;
        *(fvec4*)(fdst + 64 + tc * 4) = w1;
        unsigned short h0[4], h1[4];
#pragma unroll
        for (int i = 0; i < 4; ++i) { h0[i] = bf16r(v0[i]); h1[i] = bf16r(v1[i]); }
        u16x4 H0 = {h0[0], h0[1], h0[2], h0[3]};
        u16x4 H1 = {h1[0], h1[1], h1[2], h1[3]};
        if (s == 1) {   // k -> Apack, plain hi layout (128 shorts/row)
          unsigned short* dst = Apack + (size_t)row * 128;
          *(u16x4*)(dst + tc * 4) = H0;
          *(u16x4*)(dst + 64 + tc * 4) = H1;
        } else {        // q -> Bpack, group-swizzled hi (128 shorts/row)
          int jm = row & 7;
          int p0 = (((tc >> 1) ^ jm) << 3) | ((tc & 1) << 2);
          int p1 = (((8 + (tc >> 1)) ^ jm) << 3) | ((tc & 1) << 2);
          unsigned short* dst = Bpack + (size_t)row * 128;
          *(u16x4*)(dst + p0) = H0;
          *(u16x4*)(dst + p1) = H1;
        }
      }
    }
  }
}

// =====================================================================
// K2: hi.hi bf16 GEMM (K=128), per-LANE top-22 of EXACT (f32, j) pairs.
// grid 512 = 256 row-tiles(64 rows) x 2 j-halves; 512 thr = 8 waves.
// r11 structure (VGPR 64 -> 2 blocks/CU) with the +~4 VGPR cost of the
// kg-pre-reduced threshold paid by M_TOP 24->22 (margin-2, 7.5 sigma;
// M=22 correctness measured in r14). launch_bounds (512,2) as r11 --
// (512,8) in r14 capped VGPR at 32 and spilled catastrophically.
// =====================================================================
__global__ __launch_bounds__(512, 2) void k2_simtopk(
    const unsigned short* __restrict__ Apack, const unsigned short* __restrict__ Bpack,
    float* __restrict__ plv, int* __restrict__ pli)
{
  extern __shared__ char lds[];                   // 65536 staging + 256 thr
  unsigned* thr = (unsigned*)(lds + 65536);       // [64], mapped domain
  float* exv = (float*)lds;                       // epilogue overlay on buf0
  int*   exj = (int*)(lds + 6144);                // epilogue overlay on buf0

  const int t = threadIdx.x;
  const int lane = t & 63, wid = t >> 6;
  const int wjj = wid & 1, wii = wid >> 1;        // wjj 0..1, wii 0..3
  const int tile = blockIdx.x >> 1, jh = blockIdx.x & 1;
  const int rbase = tile * 64;
  const int jstart = jh * 8192;
  const int l15 = lane & 15, kg = lane >> 4;
  const int row = wii * 16 + l15;                 // this lane's row (0..63)

  if (t < 64) thr[t] = fmap(-3.0e38f);

  // ---- k-hi fragment: ONE row per lane (B operand col = l15) ----
  u16x8 kh[4];
  {
    const unsigned short* arow = Apack + (size_t)(rbase + row) * 128;
#pragma unroll
    for (int ks = 0; ks < 4; ++ks)
      kh[ks] = *(const u16x8*)(arow + ks * 32 + kg * 8);
  }

  // ---- per-lane top-22 (exact value, global j), descending ----
  float lv[M_TOP]; int li[M_TOP];
#pragma unroll
  for (int s = 0; s < M_TOP; ++s) { lv[s] = -3.0e38f; li[s] = 0; }

  auto insert = [&](float v, int j) {
    float cv = v; int ci = j;
#pragma unroll
    for (int s = 0; s < M_TOP; ++s) {
      bool m = cv > lv[s];
      float tv = lv[s]; int ti = li[s];
      lv[s] = m ? cv : tv; li[s] = m ? ci : ti;
      cv = m ? tv : cv;   ci = m ? ti : ci;
    }
  };

  // ---- per-lane LDS byte offsets for q-frags (XOR bank swizzle) ----
  int loff[4];
#pragma unroll
  for (int ksl = 0; ksl < 4; ++ksl)
    loff[ksl] = l15 * 256 + ((ksl * 64 + kg * 16) ^ ((l15 & 7) << 4));

  auto stage = [&](int ch) {
    if (ch >= NCHUNK) ch -= NCHUNK;   // tail wrap: dummy re-stage keeps vmcnt math
    int jb = jstart + ch * 128;
    char* base = lds + (ch & 1) * 32768;
#pragma unroll
    for (int i = 0; i < 4; ++i) {
      int L = (i * 512 + t) * 16;
      int r2 = L >> 8, bir = L & 255;
      gload_lds16((const char*)Bpack + (size_t)(jb + r2) * 256 + bir, base + L);
    }
  };

  // prologue: two chunks in flight (4 loads each)
  stage(0);
  stage(1);

  for (int chunk = 0; chunk < NCHUNK; ++chunk) {
    // buf landed; prior ds writes (thr init / thr atomics) drained for visibility
    asm volatile("s_waitcnt vmcnt(4) lgkmcnt(0)" ::: "memory");
    __builtin_amdgcn_s_barrier();                 // (a) buf + thr coherent
    MEMFENCE;

    unsigned mthr = thr[row];                     // broadcast read; used post-MFMA

    f32x4 acc[4];
#pragma unroll
    for (int jj = 0; jj < 4; ++jj) acc[jj] = (f32x4){0.f, 0.f, 0.f, 0.f};

    const char* buf = lds + (chunk & 1) * 32768 + wjj * 16384;
#pragma unroll
    for (int ksl = 0; ksl < 4; ++ksl) {
      bf16x8 q[4];
#pragma unroll
      for (int jj = 0; jj < 4; ++jj)
        q[jj] = __builtin_bit_cast(bf16x8, *(const u16x8*)(buf + jj * 4096 + loff[ksl]));
#pragma unroll
      for (int jj = 0; jj < 4; ++jj)
        acc[jj] = __builtin_amdgcn_mfma_f32_16x16x32_bf16(
            q[jj], __builtin_bit_cast(bf16x8, kh[ksl]), acc[jj], 0, 0, 0);
    }

    BARRIER_LG;                                   // (b) buf reads done
    stage(chunk + 2);                             // overwrite consumed buffer

    const float thrf = funmap(mthr);

    // ---- per-jj candidate masks + drain (in-loop mask: short liveness) ----
    const int jb2 = jstart + chunk * 128 + wjj * 64 + kg * 4;
#pragma unroll
    for (int jj = 0; jj < 4; ++jj) {
      f32x4 f = acc[jj];
      unsigned mj = 0;
#pragma unroll
      for (int r = 0; r < 4; ++r)
        mj |= (f[r] > thrf) ? (1u << r) : 0u;
      while (mj) {
        int r = __builtin_ctz(mj); mj &= mj - 1;
        float v01 = (r & 1) ? f[1] : f[0];
        float v23 = (r & 1) ? f[3] : f[2];
        float v = (r & 2) ? v23 : v01;
        if (v > lv[M_TOP - 1]) insert(v, jb2 + jj * 16 + r);
      }
    }

    // ---- publish row threshold: pre-reduce over 4 kg lanes, 1 atomic ----
    {
      float th = lv[M_TOP - 1];
      th = fmaxf(th, __shfl_xor(th, 16, 64));
      th = fmaxf(th, __shfl_xor(th, 32, 64));
      if (kg == 0 && th > thrf) atomicMax(&thr[row], fmap(th));
    }
  }
  asm volatile("s_waitcnt vmcnt(0)" ::: "memory");    // my tail dummy stages done

  // ---- merge the 4 kg-lane lists of each row (xor 16, then 32) ----
  for (int d = 16; d <= 32; d <<= 1) {
    float sv[M_TOP]; int sj[M_TOP];
#pragma unroll
    for (int s = 0; s < M_TOP; ++s) { sv[s] = lv[s]; sj[s] = li[s]; }
#pragma unroll
    for (int s = 0; s < M_TOP; ++s) {
      float pv = __shfl_xor(sv[s], d, 64);
      int pj = __shfl_xor(sj[s], d, 64);
      if (pv > lv[M_TOP - 1]) insert(pv, pj);
    }
  }

  __builtin_amdgcn_s_barrier();   // ALL waves' dummy-stage writes to buf0 done
  MEMFENCE;

  // ---- cross-wjj merge via LDS overlay; wjj==0 kg==0 lanes finish ----
  if (wjj == 1 && kg == 0) {
#pragma unroll
    for (int s = 0; s < M_TOP; ++s) {
      exv[row * M_TOP + s] = lv[s];
      exj[row * M_TOP + s] = li[s];
    }
  }
  BARRIER_LG;   // partner lists visible block-wide
  if (wjj == 0 && kg == 0) {
    for (int s = 0; s < M_TOP; ++s) {
      float pv = exv[row * M_TOP + s];
      if (!(pv > lv[M_TOP - 1])) break;   // descending -> done
      insert(pv, exj[row * M_TOP + s]);
    }
    float* pv = plv + ((size_t)jh * NDIM + rbase + row) * M_TOP;
    int* pi = pli + ((size_t)jh * NDIM + rbase + row) * M_TOP;
#pragma unroll
    for (int s = 0; s < M_TOP; ++s) { pv[s] = lv[s]; pi[s] = li[s]; }
  }
}

// =====================================================================
// K2c: merge 2x22 hi-lists -> top-22, rescore exact fp32 (qf,kf),
//      select true top-20 + softmax. 64 rows per block.
// =====================================================================
__global__ __launch_bounds__(256) void k2c_rescore(
    const float* __restrict__ plv, const int* __restrict__ pli,
    const float* __restrict__ qf, const float* __restrict__ kf,
    float* __restrict__ score, int* __restrict__ idx)
{
  __shared__ int   midx[64][M_TOP];
  __shared__ float simv[64][M_TOP];
  const int t = threadIdx.x;
  const int rbase = blockIdx.x * 64;

  if (t < 64) {
    int r = rbase + t;
    const float* v0 = plv + ((size_t)0 * NDIM + r) * M_TOP;
    const float* v1 = plv + ((size_t)1 * NDIM + r) * M_TOP;
    const int* i0 = pli + ((size_t)0 * NDIM + r) * M_TOP;
    const int* i1 = pli + ((size_t)1 * NDIM + r) * M_TOP;
    int p0 = 0, p1 = 0;
    float a = v0[0], b = v1[0];
#pragma unroll
    for (int s = 0; s < M_TOP; ++s) {
      bool ta = (a >= b);
      midx[t][s] = ta ? i0[p0] : i1[p1];
      if (ta) { ++p0; a = (p0 < M_TOP) ? v0[p0] : -3.0e38f; }
      else    { ++p1; b = (p1 < M_TOP) ? v1[p1] : -3.0e38f; }
    }
  }
  __syncthreads();
  {
    int r = t >> 2, g = t & 3;
    const float* krow = kf + (size_t)(rbase + r) * 128;
#pragma unroll
    for (int s = 0; s < 6; ++s) {
      int c = g * 6 + s;
      if (c >= M_TOP) break;
      int j = midx[r][c];
      const float* qrow = qf + (size_t)j * 128;
      fvec4 a4 = {0.f, 0.f, 0.f, 0.f};
#pragma unroll
      for (int i = 0; i < 32; ++i) {
        fvec4 kv = *(const fvec4*)(krow + i * 4);
        fvec4 qv = *(const fvec4*)(qrow + i * 4);
        a4 += kv * qv;
      }
      simv[r][c] = a4[0] + a4[1] + a4[2] + a4[3];
    }
  }
  __syncthreads();
  if (t < 64) {
    float lv[20]; int li[20];
#pragma unroll
    for (int s = 0; s < 20; ++s) { lv[s] = -3.0e38f; li[s] = 0; }
    for (int c = 0; c < M_TOP; ++c) {
      float v = simv[t][c]; int j = midx[t][c];
      if (v > lv[19]) {
        float cv = v; int ci = j;
#pragma unroll
        for (int s = 0; s < 20; ++s) {
          bool m = cv > lv[s];
          float tv = lv[s]; int ti = li[s];
          lv[s] = m ? cv : tv; li[s] = m ? ci : ti;
          cv = m ? tv : cv;   ci = m ? ti : ci;
        }
      }
    }
    float vmax = lv[0], sum = 0.f;
    float e[20];
#pragma unroll
    for (int s = 0; s < 20; ++s) { e[s] = expf(lv[s] - vmax); sum += e[s]; }
    float inv = 1.0f / sum;
    float* sc = score + (size_t)(rbase + t) * 20;
    int* ix = idx + (size_t)(rbase + t) * 20;
#pragma unroll
    for (int s = 0; s < 20; ++s) { sc[s] = e[s] * inv; ix[s] = li[s]; }
  }
}

// =====================================================================
// K3a: R[i] = sum_k score_k * relu(Am_i + Bm_{j_k})
// =====================================================================
__global__ __launch_bounds__(256) void k3a_gather(
    const float* __restrict__ Am, const float* __restrict__ Bm,
    const float* __restrict__ score, const int* __restrict__ idx,
    float* __restrict__ R)
{
  int t = threadIdx.x;
  int node = blockIdx.x * 32 + (t >> 3);
  int c0 = (t & 7) * 16;
  const float* am = Am + (size_t)node * 128 + c0;
  fvec4 a[4], r[4];
#pragma unroll
  for (int i = 0; i < 4; ++i) {
    a[i] = *(const fvec4*)(am + 4 * i);
    r[i] = (fvec4){0.f, 0.f, 0.f, 0.f};
  }
  const float* sc = score + (size_t)node * 20;
  const int* ix = idx + (size_t)node * 20;
  for (int k = 0; k < 20; ++k) {
    int j = ix[k]; float s = sc[k];
    const float* bm = Bm + (size_t)j * 128 + c0;
#pragma unroll
    for (int i = 0; i < 4; ++i) {
      fvec4 b = *(const fvec4*)(bm + 4 * i);
#pragma unroll
      for (int q = 0; q < 4; ++q)
        r[i][q] += s * fmaxf(a[i][q] + b[q], 0.f);
    }
  }
  float* outp = R + (size_t)node * 128 + c0;
#pragma unroll
  for (int i = 0; i < 4; ++i) *(fvec4*)(outp + 4 * i) = r[i];
}

// =====================================================================
// K3b: out = x + relu(XU + (R@Wm2^T + bm2)@Wu1b^T)@Wu2^T + bu2
// =====================================================================
__global__ __launch_bounds__(256, 1) void k3b_update(
    const float* __restrict__ R, const float* __restrict__ XU, const float* __restrict__ x,
    const float* __restrict__ Wm2, const float* __restrict__ bm2,
    const float* __restrict__ Wu1, const float* __restrict__ Wu2, const float* __restrict__ bu2,
    float* __restrict__ outg)
{
  extern __shared__ char lds[];
  float* in0 = (float*)lds;             // 32768
  float* in1 = (float*)(lds + 32768);   // 32768
  float* wT  = (float*)(lds + 65536);   // 65536

  const int t = threadIdx.x;
  const int rbase = blockIdx.x * 64;
  const int tr = t >> 4, tc = t & 15;

#pragma unroll
  for (int i = 0; i < 8; ++i) {
    int flat = (i * 256 + t) * 4;
    int row = flat >> 7, c = flat & 127;
    fvec4 v = *(const fvec4*)(R + (size_t)(rbase + row) * 128 + c);
    *(fvec4*)(in0 + row * 128 + (((c >> 2) ^ ((row >> 2) & 7)) << 2)) = v;
  }

  for (int s = 0; s < 3; ++s) {
    const float* W; int wstride, coff;
    if (s == 0)      { W = Wm2; wstride = 128; coff = 0; }
    else if (s == 1) { W = Wu1; wstride = 256; coff = 128; }
    else             { W = Wu2; wstride = 128; coff = 0; }

    __syncthreads();
    {
      int co = t >> 1, c0 = (t & 1) * 64;
      const float* wr = W + (size_t)co * wstride + coff + c0;
#pragma unroll
      for (int i = 0; i < 16; ++i) {
        fvec4 v = *(const fvec4*)(wr + 4 * i);
        wT[(c0 + 4 * i + 0) * 128 + co] = v[0];
        wT[(c0 + 4 * i + 1) * 128 + co] = v[1];
        wT[(c0 + 4 * i + 2) * 128 + co] = v[2];
        wT[(c0 + 4 * i + 3) * 128 + co] = v[3];
      }
    }
    __syncthreads();

    const float* in = (s == 1) ? in1 : in0;
    float acc[4][8];
#pragma unroll
    for (int rr = 0; rr < 4; ++rr)
#pragma unroll
      for (int i = 0; i < 8; ++i) acc[rr][i] = 0.f;

    for (int cq = 0; cq < 32; ++cq) {
      fvec4 xv[4];
#pragma unroll
      for (int rr = 0; rr < 4; ++rr)
        xv[rr] = *(const fvec4*)(in + (tr * 4 + rr) * 128 + ((cq ^ (tr & 7)) << 2));
#pragma unroll
      for (int j = 0; j < 4; ++j) {
        int c = cq * 4 + j;
        fvec4 wa = *(const fvec4*)(wT + c * 128 + tc * 4);
        fvec4 wb = *(const fvec4*)(wT + c * 128 + 64 + tc * 4);
#pragma unroll
        for (int rr = 0; rr < 4; ++rr) {
          float xj = xv[rr][j];
#pragma unroll
          for (int i = 0; i < 4; ++i) {
            acc[rr][i]     += xj * wa[i];
            acc[rr][4 + i] += xj * wb[i];
          }
        }
      }
    }

#pragma unroll
    for (int rr = 0; rr < 4; ++rr) {
      int row = rbase + tr * 4 + rr;
      int lrow = tr * 4 + rr;
      int q0 = tc ^ (tr & 7);
      int q1 = (16 + tc) ^ (tr & 7);
      if (s == 0) {
        fvec4 b0 = *(const fvec4*)(bm2 + tc * 4);
        fvec4 b1 = *(const fvec4*)(bm2 + 64 + tc * 4);
        fvec4 w0, w1;
#pragma unroll
        for (int i = 0; i < 4; ++i) { w0[i] = acc[rr][i] + b0[i]; w1[i] = acc[rr][4 + i] + b1[i]; }
        *(fvec4*)(in1 + lrow * 128 + q0 * 4) = w0;
        *(fvec4*)(in1 + lrow * 128 + q1 * 4) = w1;
      } else if (s == 1) {
        fvec4 x0 = *(const fvec4*)(XU + (size_t)row * 128 + tc * 4);
        fvec4 x1 = *(const fvec4*)(XU + (size_t)row * 128 + 64 + tc * 4);
        fvec4 w0, w1;
#pragma unroll
        for (int i = 0; i < 4; ++i) {
          w0[i] = fmaxf(acc[rr][i] + x0[i], 0.f);
          w1[i] = fmaxf(acc[rr][4 + i] + x1[i], 0.f);
        }
        *(fvec4*)(in0 + lrow * 128 + q0 * 4) = w0;
        *(fvec4*)(in0 + lrow * 128 + q1 * 4) = w1;
      } else {
        fvec4 b0 = *(const fvec4*)(bu2 + tc * 4);
        fvec4 b1 = *(const fvec4*)(bu2 + 64 + tc * 4);
        fvec4 x0 = *(const fvec4*)(x + (size_t)row * 128 + tc * 4);
        fvec4 x1 = *(const fvec4*)(x + (size_t)row * 128 + 64 + tc * 4);
        fvec4 w0, w1;
#pragma unroll
        for (int i = 0; i < 4; ++i) {
          w0[i] = x0[i] + acc[rr][i] + b0[i];
          w1[i] = x1[i] + acc[rr][4 + i] + b1[i];
        }
        *(fvec4*)(outg + (size_t)row * 128 + tc * 4) = w0;
        *(fvec4*)(outg + (size_t)row * 128 + 64 + tc * 4) = w1;
      }
    }
    __syncthreads();
  }
}

// =====================================================================
// launch
// =====================================================================
extern "C" void kernel_launch(void* const* d_in, const int* in_sizes, int n_in,
                              void* d_out, int out_size, void* d_ws, size_t ws_size,
                              hipStream_t stream) {
  const float* x   = (const float*)d_in[0];
  const float* Wq  = (const float*)d_in[1];
  const float* bq  = (const float*)d_in[2];
  const float* Wk  = (const float*)d_in[3];
  const float* bk  = (const float*)d_in[4];
  const float* Wm1 = (const float*)d_in[5];
  const float* bm1 = (const float*)d_in[6];
  const float* Wm2 = (const float*)d_in[7];
  const float* bm2 = (const float*)d_in[8];
  const float* Wu1 = (const float*)d_in[9];
  const float* bu1 = (const float*)d_in[10];
  const float* Wu2 = (const float*)d_in[11];
  const float* bu2 = (const float*)d_in[12];
  float* outp = (float*)d_out;

  const size_t NN = NDIM;
  char* w = (char*)d_ws;
  unsigned short* Apack = (unsigned short*)w; w += NN * 128 * 2;
  unsigned short* Bpack = (unsigned short*)w; w += NN * 128 * 2;
  float* qf = (float*)w; w += NN * 128 * 4;
  float* kf = (float*)w; w += NN * 128 * 4;
  float* Am = (float*)w; w += NN * 128 * 4;
  float* Bm = (float*)w; w += NN * 128 * 4;
  float* XU = (float*)w; w += NN * 128 * 4;
  char* w_plv = w;
  float* plv = (float*)w; w += 4 * NN * M_TOP * 4;   // (2 used; 4 kept for R overlay room)
  int* pli = (int*)w; w += 4 * NN * M_TOP * 4;
  float* score = (float*)w; w += NN * 20 * 4;
  int* idxb = (int*)w; w += NN * 20 * 4;
  float* R = (float*)w_plv;   // overlays plv/pli (dead after k2c)

  hipFuncSetAttribute((const void*)k1_linears, hipFuncAttributeMaxDynamicSharedMemorySize, 98304);
  hipFuncSetAttribute((const void*)k2_simtopk, hipFuncAttributeMaxDynamicSharedMemorySize, 65792);
  hipFuncSetAttribute((const void*)k3b_update, hipFuncAttributeMaxDynamicSharedMemorySize, 131072);

  k1_linears<<<256, 256, 98304, stream>>>(x, Wq, bq, Wk, bk, Wm1, bm1, Wu1, bu1,
                                          Apack, Bpack, qf, kf, Am, Bm, XU);
  k2_simtopk<<<512, 512, 65792, stream>>>(Apack, Bpack, plv, pli);
  k2c_rescore<<<256, 256, 0, stream>>>(plv, pli, qf, kf, score, idxb);
  k3a_gather<<<512, 256, 0, stream>>>(Am, Bm, score, idxb, R);
  k3b_update<<<256, 256, 131072, stream>>>(R, XU, x, Wm2, bm2, Wu1, Wu2, bu2, outp);
}

// Round 17
// 566.587 us; speedup vs baseline: 3.0260x; 1.2138x over previous
//
#include <hip/hip_runtime.h>
#include <stdint.h>

#define NDIM 16384
#define M_TOP 24
#define NCHUNK 64

typedef float  fvec4  __attribute__((ext_vector_type(4)));
typedef float  f32x4  __attribute__((ext_vector_type(4)));
typedef __bf16 bf16x8 __attribute__((ext_vector_type(8)));
typedef unsigned short u16x8 __attribute__((ext_vector_type(8)));
typedef unsigned short u16x4 __attribute__((ext_vector_type(4)));

static_assert(sizeof(bf16x8) == 16, "bf16x8 must be 16B");
static_assert(sizeof(u16x8) == 16, "u16x8 must be 16B");

// ---------- helpers ----------

__device__ __forceinline__ unsigned short bf16r(float x) {
  unsigned u = __builtin_bit_cast(unsigned, x);
  return (unsigned short)((u + 0x7FFFu + ((u >> 16) & 1u)) >> 16);
}

// monotone f32 <-> u32 order-preserving map (exact, bijective)
__device__ __forceinline__ unsigned fmap(float x) {
  unsigned u = __builtin_bit_cast(unsigned, x);
  return u ^ (unsigned)(((int)u >> 31) | (int)0x80000000);
}
__device__ __forceinline__ float funmap(unsigned m) {
  unsigned u = (m & 0x80000000u) ? (m ^ 0x80000000u) : ~m;
  return __builtin_bit_cast(float, u);
}

// global -> LDS direct copy, 16B per lane (linear dest per wave)
__device__ __forceinline__ void gload_lds16(const void* g, void* l) {
  typedef __attribute__((address_space(1))) const unsigned int gas_u32;
  typedef __attribute__((address_space(3))) unsigned int las_u32;
  __builtin_amdgcn_global_load_lds((gas_u32*)(uintptr_t)g,
                                   (las_u32*)(unsigned)(uintptr_t)l, 16, 0, 0);
}

#define MEMFENCE asm volatile("" ::: "memory")
#define BARRIER_LG do { asm volatile("s_waitcnt lgkmcnt(0)" ::: "memory"); \
                        __builtin_amdgcn_s_barrier(); MEMFENCE; } while (0)

// =====================================================================
// K1: fused linears: q->qf(fp32)+Bpack(hi bf16, swizzled), k->kf+Apack,
//     Am = x@Wm1a^T, Bm = x@Wm1b^T + bm1, XU = x@Wu1a^T + bu1
// =====================================================================
__global__ __launch_bounds__(256, 1) void k1_linears(
    const float* __restrict__ x,
    const float* __restrict__ Wq, const float* __restrict__ bq,
    const float* __restrict__ Wk, const float* __restrict__ bk,
    const float* __restrict__ Wm1, const float* __restrict__ bm1,
    const float* __restrict__ Wu1, const float* __restrict__ bu1,
    unsigned short* __restrict__ Apack, unsigned short* __restrict__ Bpack,
    float* __restrict__ qf, float* __restrict__ kf,
    float* __restrict__ Am, float* __restrict__ Bm, float* __restrict__ XU)
{
  extern __shared__ char lds[];
  float* xs = (float*)lds;              // 32768 B, [64][128] quad-swizzled
  float* wT = (float*)(lds + 32768);    // 65536 B, [c][co]

  const int t = threadIdx.x;
  const int rbase = blockIdx.x * 64;
  const int tr = t >> 4, tc = t & 15;

#pragma unroll
  for (int i = 0; i < 8; ++i) {
    int flat = (i * 256 + t) * 4;
    int row = flat >> 7, c = flat & 127;
    fvec4 v = *(const fvec4*)(x + (size_t)(rbase + row) * 128 + c);
    int q = (c >> 2) ^ ((row >> 2) & 7);
    *(fvec4*)(xs + row * 128 + q * 4) = v;
  }

  for (int s = 0; s < 5; ++s) {
    const float* W; int wstride, coff; const float* bias;
    if (s == 0)      { W = Wq;  wstride = 128; coff = 0;   bias = bq; }
    else if (s == 1) { W = Wk;  wstride = 128; coff = 0;   bias = bk; }
    else if (s == 2) { W = Wm1; wstride = 256; coff = 0;   bias = nullptr; }
    else if (s == 3) { W = Wm1; wstride = 256; coff = 128; bias = bm1; }
    else             { W = Wu1; wstride = 256; coff = 0;   bias = bu1; }

    __syncthreads();
    {
      int co = t >> 1, c0 = (t & 1) * 64;
      const float* wr = W + (size_t)co * wstride + coff + c0;
#pragma unroll
      for (int i = 0; i < 16; ++i) {
        fvec4 v = *(const fvec4*)(wr + 4 * i);
        wT[(c0 + 4 * i + 0) * 128 + co] = v[0];
        wT[(c0 + 4 * i + 1) * 128 + co] = v[1];
        wT[(c0 + 4 * i + 2) * 128 + co] = v[2];
        wT[(c0 + 4 * i + 3) * 128 + co] = v[3];
      }
    }
    __syncthreads();

    float acc[4][8];
#pragma unroll
    for (int rr = 0; rr < 4; ++rr)
#pragma unroll
      for (int i = 0; i < 8; ++i) acc[rr][i] = 0.f;

    for (int cq = 0; cq < 32; ++cq) {
      fvec4 xv[4];
#pragma unroll
      for (int rr = 0; rr < 4; ++rr)
        xv[rr] = *(const fvec4*)(xs + (tr * 4 + rr) * 128 + ((cq ^ (tr & 7)) << 2));
#pragma unroll
      for (int j = 0; j < 4; ++j) {
        int c = cq * 4 + j;
        fvec4 wa = *(const fvec4*)(wT + c * 128 + tc * 4);
        fvec4 wb = *(const fvec4*)(wT + c * 128 + 64 + tc * 4);
#pragma unroll
        for (int rr = 0; rr < 4; ++rr) {
          float xj = xv[rr][j];
#pragma unroll
          for (int i = 0; i < 4; ++i) {
            acc[rr][i]     += xj * wa[i];
            acc[rr][4 + i] += xj * wb[i];
          }
        }
      }
    }

    float ba[4] = {0, 0, 0, 0}, bb[4] = {0, 0, 0, 0};
    if (bias) {
      fvec4 t0 = *(const fvec4*)(bias + tc * 4);
      fvec4 t1 = *(const fvec4*)(bias + 64 + tc * 4);
#pragma unroll
      for (int i = 0; i < 4; ++i) { ba[i] = t0[i]; bb[i] = t1[i]; }
    }

#pragma unroll
    for (int rr = 0; rr < 4; ++rr) {
      int row = rbase + tr * 4 + rr;
      float v0[4], v1[4];
#pragma unroll
      for (int i = 0; i < 4; ++i) {
        v0[i] = acc[rr][i] + ba[i];
        v1[i] = acc[rr][4 + i] + bb[i];
      }
      fvec4 w0 = {v0[0], v0[1], v0[2], v0[3]};
      fvec4 w1 = {v1[0], v1[1], v1[2], v1[3]};
      if (s >= 2) {
        float* dst = (s == 2 ? Am : (s == 3 ? Bm : XU)) + (size_t)row * 128;
        *(fvec4*)(dst + tc * 4) = w0;
        *(fvec4*)(dst + 64 + tc * 4) = w1;
      } else {
        float* fdst = (s == 0 ? qf : kf) + (size_t)row * 128;
        *(fvec4*)(fdst + tc * 4) = w0;
        *(fvec4*)(fdst + 64 + tc * 4) = w1;
        unsigned short h0[4], h1[4];
#pragma unroll
        for (int i = 0; i < 4; ++i) { h0[i] = bf16r(v0[i]); h1[i] = bf16r(v1[i]); }
        u16x4 H0 = {h0[0], h0[1], h0[2], h0[3]};
        u16x4 H1 = {h1[0], h1[1], h1[2], h1[3]};
        if (s == 1) {   // k -> Apack, plain hi layout (128 shorts/row)
          unsigned short* dst = Apack + (size_t)row * 128;
          *(u16x4*)(dst + tc * 4) = H0;
          *(u16x4*)(dst + 64 + tc * 4) = H1;
        } else {        // q -> Bpack, group-swizzled hi (128 shorts/row)
          int jm = row & 7;
          int p0 = (((tc >> 1) ^ jm) << 3) | ((tc & 1) << 2);
          int p1 = (((8 + (tc >> 1)) ^ jm) << 3) | ((tc & 1) << 2);
          unsigned short* dst = Bpack + (size_t)row * 128;
          *(u16x4*)(dst + p0) = H0;
          *(u16x4*)(dst + p1) = H1;
        }
      }
    }
  }
}

// =====================================================================
// K2: hi.hi bf16 GEMM (K=128), per-LANE top-24 of PACKED u32 keys:
//   key = ((fmap(v)+0x1000) & 0xFFFFE000) | j13   (19 value bits, 13b j)
// grid 512 = 256 row-tiles(64 rows) x 2 j-halves; 512 thr = 8 waves.
// r15 skeleton; list payload = u32 keys (insert = 24 max/min pairs).
// Mask guard uses thrf = funmap(mthr & ~0x1FFF) -- the FLOOR of the
// 24th key's quantum, so no mask-level false reject is possible vs the
// key ordering (any key-beating candidate has fmap(v) > Q24 => v > thrf).
// Registers: lk 24 + kh 16 + misc ~18 < 64 (the residency cliff).
// =====================================================================
__global__ __launch_bounds__(512, 2) void k2_simtopk(
    const unsigned short* __restrict__ Apack, const unsigned short* __restrict__ Bpack,
    unsigned* __restrict__ plv)
{
  extern __shared__ char lds[];                   // 65536 staging + 256 thr
  unsigned* thr = (unsigned*)(lds + 65536);       // [64], key domain
  unsigned* exv = (unsigned*)lds;                 // epilogue overlay on buf0

  const int t = threadIdx.x;
  const int lane = t & 63, wid = t >> 6;
  const int wjj = wid & 1, wii = wid >> 1;        // wjj 0..1, wii 0..3
  const int tile = blockIdx.x >> 1, jh = blockIdx.x & 1;
  const int rbase = tile * 64;
  const int jstart = jh * 8192;
  const int l15 = lane & 15, kg = lane >> 4;
  const int row = wii * 16 + l15;                 // this lane's row (0..63)

  if (t < 64) thr[t] = fmap(-3.0e38f);            // NOT 0: funmap(0) is NaN

  // ---- k-hi fragment: ONE row per lane (B operand col = l15) ----
  u16x8 kh[4];
  {
    const unsigned short* arow = Apack + (size_t)(rbase + row) * 128;
#pragma unroll
    for (int ks = 0; ks < 4; ++ks)
      kh[ks] = *(const u16x8*)(arow + ks * 32 + kg * 8);
  }

  // ---- per-lane top-24 packed keys, descending; sentinel 0 ----
  unsigned lk[M_TOP];
#pragma unroll
  for (int s = 0; s < M_TOP; ++s) lk[s] = 0u;

  auto insert = [&](unsigned k) {
    unsigned cv = k;
#pragma unroll
    for (int s = 0; s < M_TOP; ++s) {
      unsigned mx = cv > lk[s] ? cv : lk[s];
      unsigned mn = cv > lk[s] ? lk[s] : cv;
      lk[s] = mx; cv = mn;
    }
  };

  // ---- per-lane LDS byte offsets for q-frags (XOR bank swizzle) ----
  int loff[4];
#pragma unroll
  for (int ksl = 0; ksl < 4; ++ksl)
    loff[ksl] = l15 * 256 + ((ksl * 64 + kg * 16) ^ ((l15 & 7) << 4));

  auto stage = [&](int ch) {
    if (ch >= NCHUNK) ch -= NCHUNK;   // tail wrap: dummy re-stage keeps vmcnt math
    int jb = jstart + ch * 128;
    char* base = lds + (ch & 1) * 32768;
#pragma unroll
    for (int i = 0; i < 4; ++i) {
      int L = (i * 512 + t) * 16;
      int r2 = L >> 8, bir = L & 255;
      gload_lds16((const char*)Bpack + (size_t)(jb + r2) * 256 + bir, base + L);
    }
  };

  // prologue: two chunks in flight (4 loads each)
  stage(0);
  stage(1);

  for (int chunk = 0; chunk < NCHUNK; ++chunk) {
    // buf landed; prior ds writes (thr init / thr atomics) drained for visibility
    asm volatile("s_waitcnt vmcnt(4) lgkmcnt(0)" ::: "memory");
    __builtin_amdgcn_s_barrier();                 // (a) buf + thr coherent
    MEMFENCE;

    unsigned mthr = thr[row];                     // broadcast read; used post-MFMA

    f32x4 acc[4];
#pragma unroll
    for (int jj = 0; jj < 4; ++jj) acc[jj] = (f32x4){0.f, 0.f, 0.f, 0.f};

    const char* buf = lds + (chunk & 1) * 32768 + wjj * 16384;
#pragma unroll
    for (int ksl = 0; ksl < 4; ++ksl) {
      bf16x8 q[4];
#pragma unroll
      for (int jj = 0; jj < 4; ++jj)
        q[jj] = __builtin_bit_cast(bf16x8, *(const u16x8*)(buf + jj * 4096 + loff[ksl]));
#pragma unroll
      for (int jj = 0; jj < 4; ++jj)
        acc[jj] = __builtin_amdgcn_mfma_f32_16x16x32_bf16(
            q[jj], __builtin_bit_cast(bf16x8, kh[ksl]), acc[jj], 0, 0, 0);
    }

    BARRIER_LG;                                   // (b) buf reads done
    stage(chunk + 2);                             // overwrite consumed buffer

    // conservative float guard: FLOOR of the 24th key's value quantum
    const float thrf = funmap(mthr & 0xFFFFE000u);

    // ---- per-jj candidate masks + drain (in-loop mask: short liveness) ----
    const int jb2 = chunk * 128 + wjj * 64 + kg * 4;   // 13-bit in-half j base
#pragma unroll
    for (int jj = 0; jj < 4; ++jj) {
      f32x4 f = acc[jj];
      unsigned mj = 0;
#pragma unroll
      for (int r = 0; r < 4; ++r)
        mj |= (f[r] > thrf) ? (1u << r) : 0u;
      while (mj) {
        int r = __builtin_ctz(mj); mj &= mj - 1;
        float v01 = (r & 1) ? f[1] : f[0];
        float v23 = (r & 1) ? f[3] : f[2];
        float v = (r & 2) ? v23 : v01;
        unsigned key = ((fmap(v) + 0x1000u) & 0xFFFFE000u)
                       | (unsigned)(jb2 + jj * 16 + r);
        if (key > lk[M_TOP - 1]) insert(key);
      }
    }

    // ---- publish row threshold: pre-reduce over 4 kg lanes, 1 atomic ----
    {
      unsigned th = lk[M_TOP - 1];
      unsigned ta = (unsigned)__shfl_xor((int)th, 16, 64); th = ta > th ? ta : th;
      unsigned tb = (unsigned)__shfl_xor((int)th, 32, 64); th = tb > th ? tb : th;
      if (kg == 0 && th > mthr) atomicMax(&thr[row], th);
    }
  }
  asm volatile("s_waitcnt vmcnt(0)" ::: "memory");    // my tail dummy stages done

  // ---- merge the 4 kg-lane lists of each row (xor 16, then 32) ----
  for (int d = 16; d <= 32; d <<= 1) {
    unsigned sv[M_TOP];
#pragma unroll
    for (int s = 0; s < M_TOP; ++s) sv[s] = lk[s];
#pragma unroll
    for (int s = 0; s < M_TOP; ++s) {
      unsigned pv = (unsigned)__shfl_xor((int)sv[s], d, 64);
      if (pv > lk[M_TOP - 1]) insert(pv);
    }
  }

  __builtin_amdgcn_s_barrier();   // ALL waves' dummy-stage writes to buf0 done
  MEMFENCE;

  // ---- cross-wjj merge via LDS overlay; wjj==0 kg==0 lanes finish ----
  if (wjj == 1 && kg == 0) {
#pragma unroll
    for (int s = 0; s < M_TOP; ++s)
      exv[row * M_TOP + s] = lk[s];
  }
  BARRIER_LG;   // partner lists visible block-wide
  if (wjj == 0 && kg == 0) {
    for (int s = 0; s < M_TOP; ++s) {
      unsigned pv = exv[row * M_TOP + s];
      if (!(pv > lk[M_TOP - 1])) break;   // descending -> done
      insert(pv);
    }
    unsigned* pv = plv + ((size_t)jh * NDIM + rbase + row) * M_TOP;
#pragma unroll
    for (int s = 0; s < M_TOP; ++s) pv[s] = lk[s];
  }
}

// =====================================================================
// K2c: decode ALL 48 keys (24 per half), rescore each in exact fp32
//      (qf,kf), select true top-20 + softmax. 64 rows per block.
//      No merge logic at all -- rescore-everything kills the tie surface.
// =====================================================================
__global__ __launch_bounds__(256) void k2c_rescore(
    const unsigned* __restrict__ plv,
    const float* __restrict__ qf, const float* __restrict__ kf,
    float* __restrict__ score, int* __restrict__ idx)
{
  __shared__ int   midx[64][2 * M_TOP];
  __shared__ float simv[64][2 * M_TOP];
  const int t = threadIdx.x;
  const int rbase = blockIdx.x * 64;

  {  // phase 1: decode keys -> global j (4 threads per row, 12 each)
    int r = t >> 2, g = t & 3;
#pragma unroll
    for (int s = 0; s < 12; ++s) {
      int c = g * 12 + s;
      int h = c / M_TOP, p = c - h * M_TOP;
      unsigned key = plv[((size_t)h * NDIM + rbase + r) * M_TOP + p];
      midx[r][c] = h * 8192 + (int)(key & 0x1FFFu);
    }
  }
  __syncthreads();
  {  // phase 2: exact fp32 rescore (12 dots per thread)
    int r = t >> 2, g = t & 3;
    const float* krow = kf + (size_t)(rbase + r) * 128;
#pragma unroll
    for (int s = 0; s < 12; ++s) {
      int c = g * 12 + s;
      int j = midx[r][c];
      const float* qrow = qf + (size_t)j * 128;
      fvec4 a4 = {0.f, 0.f, 0.f, 0.f};
#pragma unroll
      for (int i = 0; i < 32; ++i) {
        fvec4 kv = *(const fvec4*)(krow + i * 4);
        fvec4 qv = *(const fvec4*)(qrow + i * 4);
        a4 += kv * qv;
      }
      simv[r][c] = a4[0] + a4[1] + a4[2] + a4[3];
    }
  }
  __syncthreads();
  if (t < 64) {  // phase 3: true top-20 of 48 + softmax
    float lv[20]; int li[20];
#pragma unroll
    for (int s = 0; s < 20; ++s) { lv[s] = -3.0e38f; li[s] = 0; }
    for (int c = 0; c < 2 * M_TOP; ++c) {
      float v = simv[t][c]; int j = midx[t][c];
      if (v > lv[19]) {
        float cv = v; int ci = j;
#pragma unroll
        for (int s = 0; s < 20; ++s) {
          bool m = cv > lv[s];
          float tv = lv[s]; int ti = li[s];
          lv[s] = m ? cv : tv; li[s] = m ? ci : ti;
          cv = m ? tv : cv;   ci = m ? ti : ci;
        }
      }
    }
    float vmax = lv[0], sum = 0.f;
    float e[20];
#pragma unroll
    for (int s = 0; s < 20; ++s) { e[s] = expf(lv[s] - vmax); sum += e[s]; }
    float inv = 1.0f / sum;
    float* sc = score + (size_t)(rbase + t) * 20;
    int* ix = idx + (size_t)(rbase + t) * 20;
#pragma unroll
    for (int s = 0; s < 20; ++s) { sc[s] = e[s] * inv; ix[s] = li[s]; }
  }
}

// =====================================================================
// K3a: R[i] = sum_k score_k * relu(Am_i + Bm_{j_k})
// =====================================================================
__global__ __launch_bounds__(256) void k3a_gather(
    const float* __restrict__ Am, const float* __restrict__ Bm,
    const float* __restrict__ score, const int* __restrict__ idx,
    float* __restrict__ R)
{
  int t = threadIdx.x;
  int node = blockIdx.x * 32 + (t >> 3);
  int c0 = (t & 7) * 16;
  const float* am = Am + (size_t)node * 128 + c0;
  fvec4 a[4], r[4];
#pragma unroll
  for (int i = 0; i < 4; ++i) {
    a[i] = *(const fvec4*)(am + 4 * i);
    r[i] = (fvec4){0.f, 0.f, 0.f, 0.f};
  }
  const float* sc = score + (size_t)node * 20;
  const int* ix = idx + (size_t)node * 20;
  for (int k = 0; k < 20; ++k) {
    int j = ix[k]; float s = sc[k];
    const float* bm = Bm + (size_t)j * 128 + c0;
#pragma unroll
    for (int i = 0; i < 4; ++i) {
      fvec4 b = *(const fvec4*)(bm + 4 * i);
#pragma unroll
      for (int q = 0; q < 4; ++q)
        r[i][q] += s * fmaxf(a[i][q] + b[q], 0.f);
    }
  }
  float* outp = R + (size_t)node * 128 + c0;
#pragma unroll
  for (int i = 0; i < 4; ++i) *(fvec4*)(outp + 4 * i) = r[i];
}

// =====================================================================
// K3b: out = x + relu(XU + (R@Wm2^T + bm2)@Wu1b^T)@Wu2^T + bu2
// =====================================================================
__global__ __launch_bounds__(256, 1) void k3b_update(
    const float* __restrict__ R, const float* __restrict__ XU, const float* __restrict__ x,
    const float* __restrict__ Wm2, const float* __restrict__ bm2,
    const float* __restrict__ Wu1, const float* __restrict__ Wu2, const float* __restrict__ bu2,
    float* __restrict__ outg)
{
  extern __shared__ char lds[];
  float* in0 = (float*)lds;             // 32768
  float* in1 = (float*)(lds + 32768);   // 32768
  float* wT  = (float*)(lds + 65536);   // 65536

  const int t = threadIdx.x;
  const int rbase = blockIdx.x * 64;
  const int tr = t >> 4, tc = t & 15;

#pragma unroll
  for (int i = 0; i < 8; ++i) {
    int flat = (i * 256 + t) * 4;
    int row = flat >> 7, c = flat & 127;
    fvec4 v = *(const fvec4*)(R + (size_t)(rbase + row) * 128 + c);
    *(fvec4*)(in0 + row * 128 + (((c >> 2) ^ ((row >> 2) & 7)) << 2)) = v;
  }

  for (int s = 0; s < 3; ++s) {
    const float* W; int wstride, coff;
    if (s == 0)      { W = Wm2; wstride = 128; coff = 0; }
    else if (s == 1) { W = Wu1; wstride = 256; coff = 128; }
    else             { W = Wu2; wstride = 128; coff = 0; }

    __syncthreads();
    {
      int co = t >> 1, c0 = (t & 1) * 64;
      const float* wr = W + (size_t)co * wstride + coff + c0;
#pragma unroll
      for (int i = 0; i < 16; ++i) {
        fvec4 v = *(const fvec4*)(wr + 4 * i);
        wT[(c0 + 4 * i + 0) * 128 + co] = v[0];
        wT[(c0 + 4 * i + 1) * 128 + co] = v[1];
        wT[(c0 + 4 * i + 2) * 128 + co] = v[2];
        wT[(c0 + 4 * i + 3) * 128 + co] = v[3];
      }
    }
    __syncthreads();

    const float* in = (s == 1) ? in1 : in0;
    float acc[4][8];
#pragma unroll
    for (int rr = 0; rr < 4; ++rr)
#pragma unroll
      for (int i = 0; i < 8; ++i) acc[rr][i] = 0.f;

    for (int cq = 0; cq < 32; ++cq) {
      fvec4 xv[4];
#pragma unroll
      for (int rr = 0; rr < 4; ++rr)
        xv[rr] = *(const fvec4*)(in + (tr * 4 + rr) * 128 + ((cq ^ (tr & 7)) << 2));
#pragma unroll
      for (int j = 0; j < 4; ++j) {
        int c = cq * 4 + j;
        fvec4 wa = *(const fvec4*)(wT + c * 128 + tc * 4);
        fvec4 wb = *(const fvec4*)(wT + c * 128 + 64 + tc * 4);
#pragma unroll
        for (int rr = 0; rr < 4; ++rr) {
          float xj = xv[rr][j];
#pragma unroll
          for (int i = 0; i < 4; ++i) {
            acc[rr][i]     += xj * wa[i];
            acc[rr][4 + i] += xj * wb[i];
          }
        }
      }
    }

#pragma unroll
    for (int rr = 0; rr < 4; ++rr) {
      int row = rbase + tr * 4 + rr;
      int lrow = tr * 4 + rr;
      int q0 = tc ^ (tr & 7);
      int q1 = (16 + tc) ^ (tr & 7);
      if (s == 0) {
        fvec4 b0 = *(const fvec4*)(bm2 + tc * 4);
        fvec4 b1 = *(const fvec4*)(bm2 + 64 + tc * 4);
        fvec4 w0, w1;
#pragma unroll
        for (int i = 0; i < 4; ++i) { w0[i] = acc[rr][i] + b0[i]; w1[i] = acc[rr][4 + i] + b1[i]; }
        *(fvec4*)(in1 + lrow * 128 + q0 * 4) = w0;
        *(fvec4*)(in1 + lrow * 128 + q1 * 4) = w1;
      } else if (s == 1) {
        fvec4 x0 = *(const fvec4*)(XU + (size_t)row * 128 + tc * 4);
        fvec4 x1 = *(const fvec4*)(XU + (size_t)row * 128 + 64 + tc * 4);
        fvec4 w0, w1;
#pragma unroll
        for (int i = 0; i < 4; ++i) {
          w0[i] = fmaxf(acc[rr][i] + x0[i], 0.f);
          w1[i] = fmaxf(acc[rr][4 + i] + x1[i], 0.f);
        }
        *(fvec4*)(in0 + lrow * 128 + q0 * 4) = w0;
        *(fvec4*)(in0 + lrow * 128 + q1 * 4) = w1;
      } else {
        fvec4 b0 = *(const fvec4*)(bu2 + tc * 4);
        fvec4 b1 = *(const fvec4*)(bu2 + 64 + tc * 4);
        fvec4 x0 = *(const fvec4*)(x + (size_t)row * 128 + tc * 4);
        fvec4 x1 = *(const fvec4*)(x + (size_t)row * 128 + 64 + tc * 4);
        fvec4 w0, w1;
#pragma unroll
        for (int i = 0; i < 4; ++i) {
          w0[i] = x0[i] + acc[rr][i] + b0[i];
          w1[i] = x1[i] + acc[rr][4 + i] + b1[i];
        }
        *(fvec4*)(outg + (size_t)row * 128 + tc * 4) = w0;
        *(fvec4*)(outg + (size_t)row * 128 + 64 + tc * 4) = w1;
      }
    }
    __syncthreads();
  }
}

// =====================================================================
// launch
// =====================================================================
extern "C" void kernel_launch(void* const* d_in, const int* in_sizes, int n_in,
                              void* d_out, int out_size, void* d_ws, size_t ws_size,
                              hipStream_t stream) {
  const float* x   = (const float*)d_in[0];
  const float* Wq  = (const float*)d_in[1];
  const float* bq  = (const float*)d_in[2];
  const float* Wk  = (const float*)d_in[3];
  const float* bk  = (const float*)d_in[4];
  const float* Wm1 = (const float*)d_in[5];
  const float* bm1 = (const float*)d_in[6];
  const float* Wm2 = (const float*)d_in[7];
  const float* bm2 = (const float*)d_in[8];
  const float* Wu1 = (const float*)d_in[9];
  const float* bu1 = (const float*)d_in[10];
  const float* Wu2 = (const float*)d_in[11];
  const float* bu2 = (const float*)d_in[12];
  float* outp = (float*)d_out;

  const size_t NN = NDIM;
  char* w = (char*)d_ws;
  unsigned short* Apack = (unsigned short*)w; w += NN * 128 * 2;
  unsigned short* Bpack = (unsigned short*)w; w += NN * 128 * 2;
  float* qf = (float*)w; w += NN * 128 * 4;
  float* kf = (float*)w; w += NN * 128 * 4;
  float* Am = (float*)w; w += NN * 128 * 4;
  float* Bm = (float*)w; w += NN * 128 * 4;
  float* XU = (float*)w; w += NN * 128 * 4;
  char* w_plv = w;
  unsigned* plv = (unsigned*)w;
  w += NN * 128 * 4;            // reserve FULL R-size (8.4 MB >= plv's 3.1 MB)
  float* score = (float*)w; w += NN * 20 * 4;   // AFTER the R overlay region
  int* idxb = (int*)w; w += NN * 20 * 4;
  float* R = (float*)w_plv;     // overlays plv only (plv dead after k2c)

  hipFuncSetAttribute((const void*)k1_linears, hipFuncAttributeMaxDynamicSharedMemorySize, 98304);
  hipFuncSetAttribute((const void*)k2_simtopk, hipFuncAttributeMaxDynamicSharedMemorySize, 65792);
  hipFuncSetAttribute((const void*)k3b_update, hipFuncAttributeMaxDynamicSharedMemorySize, 131072);

  k1_linears<<<256, 256, 98304, stream>>>(x, Wq, bq, Wk, bk, Wm1, bm1, Wu1, bu1,
                                          Apack, Bpack, qf, kf, Am, Bm, XU);
  k2_simtopk<<<512, 512, 65792, stream>>>(Apack, Bpack, plv);
  k2c_rescore<<<256, 256, 0, stream>>>(plv, qf, kf, score, idxb);
  k3a_gather<<<512, 256, 0, stream>>>(Am, Bm, score, idxb, R);
  k3b_update<<<256, 256, 131072, stream>>>(R, XU, x, Wm2, bm2, Wu1, Wu2, bu2, outp);
}